// Round 2
// baseline (1017.033 us; speedup 1.0000x reference)
//
#include <hip/hip_runtime.h>
#include <hip/hip_bf16.h>

typedef __attribute__((ext_vector_type(8))) __bf16 bf16x8;
typedef __attribute__((ext_vector_type(8))) unsigned short u16x8;
typedef __attribute__((ext_vector_type(4))) float f32x4;
typedef __attribute__((ext_vector_type(4))) int i32x4;
typedef __attribute__((ext_vector_type(4))) unsigned int u32x4;

#define NB 4
#define NS 2048
#define NH 8
#define NHD 64
#define NDH 512

__device__ __forceinline__ unsigned short f2bf(float f) {
  union { float f; unsigned int u; } v; v.f = f;
  unsigned int r = v.u + 0x7FFFu + ((v.u >> 16) & 1u);
  return (unsigned short)(r >> 16);
}

__device__ __forceinline__ f32x4 MFMA(u16x8 a, u16x8 b, f32x4 c) {
  return __builtin_amdgcn_mfma_f32_16x16x32_bf16(
      __builtin_bit_cast(bf16x8, a), __builtin_bit_cast(bf16x8, b), c, 0, 0, 0);
}

// ---------------- prep: x->bf16, W transpose->bf16 [N,K], mask->bits ----------
__global__ __launch_bounds__(256) void prep_kernel(
    const float* __restrict__ x, const int* __restrict__ mask,
    const float* __restrict__ Wq, const float* __restrict__ Wk,
    const float* __restrict__ Wv, const float* __restrict__ Wo,
    unsigned short* __restrict__ xb, unsigned short* __restrict__ Wt,
    unsigned int* __restrict__ mb) {
  const int bid = blockIdx.x, t = threadIdx.x;
  if (bid < 2048) {
    size_t base = ((size_t)bid * 256 + t) * 8;
    f32x4 a = *(const f32x4*)(x + base);
    f32x4 b = *(const f32x4*)(x + base + 4);
    u16x8 o;
    o[0] = f2bf(a[0]); o[1] = f2bf(a[1]); o[2] = f2bf(a[2]); o[3] = f2bf(a[3]);
    o[4] = f2bf(b[0]); o[5] = f2bf(b[1]); o[6] = f2bf(b[2]); o[7] = f2bf(b[3]);
    *(u16x8*)(xb + base) = o;
  } else if (bid < 3072) {
    __shared__ float lds[32][33];
    int wb = bid - 2048;
    int mat = wb >> 8, tile = wb & 255, tr = tile >> 4, tc = tile & 15;
    const float* W = (mat == 0) ? Wq : (mat == 1) ? Wk : (mat == 2) ? Wv : Wo;
    int col = t & 31, rbase = t >> 5;
    for (int i = 0; i < 4; ++i) {
      int row = rbase + i * 8;
      lds[row][col] = W[(size_t)(tr * 32 + row) * 512 + tc * 32 + col];
    }
    __syncthreads();
    for (int i = 0; i < 4; ++i) {
      int row = rbase + i * 8;  // j-local
      Wt[((size_t)(mat * 512 + tc * 32 + row)) * 512 + tr * 32 + col] =
          f2bf(lds[col][row]);
    }
  } else {
    int widx = (bid - 3072) * 256 + t;
    const int* mp = mask + (size_t)widx * 32;
    unsigned int word = 0;
    for (int i = 0; i < 8; ++i) {
      i32x4 m = *(const i32x4*)(mp + i * 4);
      word |= (m[0] != 0 ? 1u : 0u) << (i * 4);
      word |= (m[1] != 0 ? 1u : 0u) << (i * 4 + 1);
      word |= (m[2] != 0 ? 1u : 0u) << (i * 4 + 2);
      word |= (m[3] != 0 ? 1u : 0u) << (i * 4 + 3);
    }
    mb[widx] = word;
  }
}

// ---------------- GEMM: C[M,N] = A[M,512] x Bt[N,512]^T ----------------------
// mode 0: N=1536, epilogue bias+pe, scatter to q/k/v [B,H,S,hd] bf16
// mode 1: N=512, epilogue +bo, write fp32 proj [M,512]
__global__ __launch_bounds__(256) void gemm_kernel(
    const unsigned short* __restrict__ A, const unsigned short* __restrict__ Bt,
    int mode, unsigned short* __restrict__ qb, unsigned short* __restrict__ kb,
    unsigned short* __restrict__ vb, const float* __restrict__ bq,
    const float* __restrict__ bk, const float* __restrict__ bv,
    const float* __restrict__ pe, float* __restrict__ proj,
    const float* __restrict__ bo) {
  const int t = threadIdx.x;
  const int w = t >> 6, lane = t & 63, l15 = lane & 15, quad = lane >> 4;
  const int n0 = blockIdx.x * 64, m0 = blockIdx.y * 64;
  __shared__ unsigned short a_lds[64 * 40];
  __shared__ unsigned short b_lds[64 * 40];
  f32x4 acc[4] = {};
  const int srow = t >> 2, sc8 = (t & 3) * 8;
  for (int k0 = 0; k0 < 512; k0 += 32) {
    u16x8 av = *(const u16x8*)(A + (size_t)(m0 + srow) * 512 + k0 + sc8);
    u16x8 bvv = *(const u16x8*)(Bt + (size_t)(n0 + srow) * 512 + k0 + sc8);
    __syncthreads();
    *(u16x8*)(a_lds + srow * 40 + sc8) = av;
    *(u16x8*)(b_lds + srow * 40 + sc8) = bvv;
    __syncthreads();
    u16x8 af = *(const u16x8*)(a_lds + (16 * w + l15) * 40 + quad * 8);
    for (int nt = 0; nt < 4; ++nt) {
      u16x8 bf_ = *(const u16x8*)(b_lds + (nt * 16 + l15) * 40 + quad * 8);
      acc[nt] = MFMA(af, bf_, acc[nt]);
    }
  }
  if (mode == 0) {
    for (int nt = 0; nt < 4; ++nt) {
      int j = n0 + nt * 16 + l15;
      int sel = j >> 9, jj = j & 511;
      int h = jj >> 6, hd = jj & 63;
      float bias = (sel == 0) ? bq[jj] : (sel == 1) ? bk[jj] : bv[jj];
      unsigned short* dst = (sel == 0) ? qb : (sel == 1) ? kb : vb;
      for (int r = 0; r < 4; ++r) {
        int m = m0 + 16 * w + quad * 4 + r;
        int bb = m >> 11, s = m & 2047;
        float v = acc[nt][r] + bias;
        if (sel < 2) v += pe[(size_t)s * 512 + jj];
        dst[(((size_t)bb * NH + h) * NS + s) * NHD + hd] = f2bf(v);
      }
    }
  } else {
    for (int nt = 0; nt < 4; ++nt) {
      int j = n0 + nt * 16 + l15;
      float bias = bo[j];
      for (int r = 0; r < 4; ++r) {
        int m = m0 + 16 * w + quad * 4 + r;
        proj[(size_t)m * 512 + j] = acc[nt][r] + bias;
      }
    }
  }
}

// ---------------- v [BH,S,hd] -> vT [BH,hd,S] --------------------------------
__global__ __launch_bounds__(256) void vtrans_kernel(
    const unsigned short* __restrict__ v, unsigned short* __restrict__ vT) {
  const int bh = blockIdx.y, st = blockIdx.x, t = threadIdx.x;
  const int s0 = st * 64;
  __shared__ unsigned int ldsT[64 * 36];
  int sp = t & 31, c8 = t >> 5;
  const unsigned short* vp = v + ((size_t)bh * NS + s0 + 2 * sp) * NHD + c8 * 8;
  u16x8 a = *(const u16x8*)(vp);
  u16x8 b = *(const u16x8*)(vp + NHD);
  for (int i = 0; i < 8; ++i) {
    unsigned int word = (unsigned int)a[i] | ((unsigned int)b[i] << 16);
    ldsT[(c8 * 8 + i) * 36 + sp] = word;
  }
  __syncthreads();
  int hd = t >> 2, cc = t & 3;
  u32x4 w0 = *(const u32x4*)(ldsT + hd * 36 + cc * 8);
  u32x4 w1 = *(const u32x4*)(ldsT + hd * 36 + cc * 8 + 4);
  unsigned short* op = vT + ((size_t)bh * NHD + hd) * NS + s0 + cc * 16;
  *(u32x4*)(op) = w0;
  *(u32x4*)(op + 8) = w1;
}

// ---------------- attention: per (bh, 64-row q tile) -------------------------
// Barrier-free: K/V^T fragments come straight from global (L2-resident per bh;
// LDS staging of L2-fit data was pure overhead). Only LDS use is a per-wave
// 16x64 bf16 P stripe (stride 72 shorts = 144 B, 16B-aligned rows -> legal
// ds_read_b128 and conflict-optimal: bank group = 4*(l15+quad) mod 32, 8 lanes
// per group = minimum phases). The stripe is intra-wave (wave w writes rows
// 0..15 of its stripe and reads the same rows), DS ops are wave-ordered, so a
// compiler fence replaces __syncthreads. Softmax stats are per-thread online;
// one 4-step shuffle merge after pass A.
__global__ __launch_bounds__(256, 4) void attn_kernel(
    const unsigned short* __restrict__ qg, const unsigned short* __restrict__ kg,
    const unsigned short* __restrict__ vTg, const unsigned int* __restrict__ mb,
    float* __restrict__ attnp_base, unsigned short* __restrict__ ao) {
  const int qt = blockIdx.x, bh = blockIdx.y;
  const int bb = bh >> 3, hh = bh & 7;
  const int t = threadIdx.x, w = t >> 6, lane = t & 63;
  const int l15 = lane & 15, quad = lane >> 4;
  const int sq0 = qt * 64;

  __shared__ unsigned short p_lds[4][16 * 72];  // per-wave stripe, stride 72
  unsigned short* pw = &p_lds[w][0];

  const unsigned short* qptr = qg + ((size_t)bh * NS + sq0 + 16 * w) * NHD;
  const unsigned short* kbase = kg + (size_t)bh * NS * NHD;
  const unsigned short* vtbase = vTg + (size_t)bh * NHD * NS;

  const u16x8 a0 = *(const u16x8*)(qptr + l15 * 64 + quad * 8);
  const u16x8 a1 = *(const u16x8*)(qptr + l15 * 64 + 32 + quad * 8);

  float mI[4], lI[4];
#pragma unroll
  for (int r = 0; r < 4; ++r) { mI[r] = -1e30f; lI[r] = 0.f; }
  const size_t mrow0 = ((size_t)bb * NS + sq0 + 16 * w + quad * 4) * 64;

  // pass A: per-thread online stats only (no cross-lane, no LDS, no barriers)
  for (int kt = 0; kt < 32; ++kt) {
    const unsigned short* kp = kbase + (size_t)kt * 64 * NHD;
    f32x4 sc[4];
#pragma unroll
    for (int nt = 0; nt < 4; ++nt) {
      u16x8 b0 = *(const u16x8*)(kp + (nt * 16 + l15) * 64 + quad * 8);
      u16x8 b1 = *(const u16x8*)(kp + (nt * 16 + l15) * 64 + 32 + quad * 8);
      f32x4 acc = {0.f, 0.f, 0.f, 0.f};
      acc = MFMA(a0, b0, acc);
      acc = MFMA(a1, b1, acc);
      sc[nt] = acc;
    }
    unsigned int mw0[4], mw1[4];
#pragma unroll
    for (int r = 0; r < 4; ++r) {
      mw0[r] = mb[mrow0 + (size_t)r * 64 + kt * 2];
      mw1[r] = mb[mrow0 + (size_t)r * 64 + kt * 2 + 1];
    }
    float tm[4] = {-1e30f, -1e30f, -1e30f, -1e30f};
#pragma unroll
    for (int nt = 0; nt < 4; ++nt) {
      int cl = nt * 16 + l15;
#pragma unroll
      for (int r = 0; r < 4; ++r) {
        float sv = sc[nt][r] * 0.125f;
        unsigned int wsel = (cl < 32) ? mw0[r] : mw1[r];
        if (!((wsel >> (cl & 31)) & 1u)) sv = -1e30f;
        sc[nt][r] = sv;
        tm[r] = fmaxf(tm[r], sv);
      }
    }
#pragma unroll
    for (int r = 0; r < 4; ++r) {
      float mN = fmaxf(mI[r], tm[r]);
      float sum = 0.f;
#pragma unroll
      for (int nt = 0; nt < 4; ++nt) sum += __expf(sc[nt][r] - mN);
      lI[r] = lI[r] * __expf(mI[r] - mN) + sum;
      mI[r] = mN;
    }
  }
  // merge stats across the 16 l15 lanes (they hold the same 4 rows)
#pragma unroll
  for (int off = 1; off < 16; off <<= 1) {
#pragma unroll
    for (int r = 0; r < 4; ++r) {
      float mo = __shfl_xor(mI[r], off, 64);
      float lo = __shfl_xor(lI[r], off, 64);
      float mN = fmaxf(mI[r], mo);
      lI[r] = lI[r] * __expf(mI[r] - mN) + lo * __expf(mo - mN);
      mI[r] = mN;
    }
  }
  float invl[4];
#pragma unroll
  for (int r = 0; r < 4; ++r) invl[r] = 1.0f / lI[r];

  float* attnp = attnp_base + ((size_t)bh * NS + sq0 + 16 * w) * NS;
  f32x4 oacc[4] = {};

  // pass B: recompute scores, write normalized p, accumulate O = P V
  for (int kt = 0; kt < 32; ++kt) {
    const unsigned short* kp = kbase + (size_t)kt * 64 * NHD;
    f32x4 sc[4];
#pragma unroll
    for (int nt = 0; nt < 4; ++nt) {
      u16x8 b0 = *(const u16x8*)(kp + (nt * 16 + l15) * 64 + quad * 8);
      u16x8 b1 = *(const u16x8*)(kp + (nt * 16 + l15) * 64 + 32 + quad * 8);
      f32x4 acc = {0.f, 0.f, 0.f, 0.f};
      acc = MFMA(a0, b0, acc);
      acc = MFMA(a1, b1, acc);
      sc[nt] = acc;
    }
    unsigned int mw0[4], mw1[4];
#pragma unroll
    for (int r = 0; r < 4; ++r) {
      mw0[r] = mb[mrow0 + (size_t)r * 64 + kt * 2];
      mw1[r] = mb[mrow0 + (size_t)r * 64 + kt * 2 + 1];
    }
#pragma unroll
    for (int nt = 0; nt < 4; ++nt) {
      int cl = nt * 16 + l15;
#pragma unroll
      for (int r = 0; r < 4; ++r) {
        float sv = sc[nt][r] * 0.125f;
        unsigned int wsel = (cl < 32) ? mw0[r] : mw1[r];
        if (!((wsel >> (cl & 31)) & 1u)) sv = -1e30f;
        float pv = __expf(sv - mI[r]) * invl[r];
        attnp[(size_t)(quad * 4 + r) * NS + kt * 64 + cl] = pv;
        pw[(quad * 4 + r) * 72 + cl] = f2bf(pv);
      }
    }
    // order p writes before PV reads; DS ops are in-order within a wave, so a
    // compiler fence is sufficient (no __syncthreads: stripe is wave-private)
    asm volatile("" ::: "memory");
#pragma unroll
    for (int kk = 0; kk < 64; kk += 32) {
      u16x8 af = *(const u16x8*)(pw + l15 * 72 + kk + quad * 8);
#pragma unroll
      for (int nto = 0; nto < 4; ++nto) {
        u16x8 bf_ = *(const u16x8*)(vtbase + (size_t)(nto * 16 + l15) * NS +
                                    kt * 64 + kk + quad * 8);
        oacc[nto] = MFMA(af, bf_, oacc[nto]);
      }
    }
    asm volatile("" ::: "memory");  // order PV reads before next iter's writes
  }
#pragma unroll
  for (int nto = 0; nto < 4; ++nto)
#pragma unroll
    for (int r = 0; r < 4; ++r) {
      int s = sq0 + 16 * w + quad * 4 + r;
      ao[((size_t)(bb * NS + s)) * NDH + hh * 64 + nto * 16 + l15] =
          f2bf(oacc[nto][r]);
    }
}

// ---------------- layernorm over last dim 512 --------------------------------
__global__ __launch_bounds__(256) void ln_kernel(
    const float* __restrict__ proj, const float* __restrict__ gamma,
    const float* __restrict__ beta, float* __restrict__ out) {
  const int t = threadIdx.x, w = t >> 6, lane = t & 63;
  const int row = blockIdx.x * 4 + w;
  const float* pr = proj + (size_t)row * 512 + lane * 8;
  f32x4 v0 = *(const f32x4*)(pr);
  f32x4 v1 = *(const f32x4*)(pr + 4);
  float s = 0.f, s2 = 0.f;
  for (int j = 0; j < 4; ++j) {
    s += v0[j] + v1[j];
    s2 += v0[j] * v0[j] + v1[j] * v1[j];
  }
  for (int off = 1; off < 64; off <<= 1) {
    s += __shfl_xor(s, off, 64);
    s2 += __shfl_xor(s2, off, 64);
  }
  float mu = s * (1.f / 512.f);
  float var = s2 * (1.f / 512.f) - mu * mu;
  float rs = rsqrtf(var + 1e-5f);
  f32x4 g0 = *(const f32x4*)(gamma + lane * 8);
  f32x4 g1 = *(const f32x4*)(gamma + lane * 8 + 4);
  f32x4 be0 = *(const f32x4*)(beta + lane * 8);
  f32x4 be1 = *(const f32x4*)(beta + lane * 8 + 4);
  f32x4 o0, o1;
  for (int j = 0; j < 4; ++j) {
    o0[j] = (v0[j] - mu) * rs * g0[j] + be0[j];
    o1[j] = (v1[j] - mu) * rs * g1[j] + be1[j];
  }
  float* op = out + (size_t)row * 512 + lane * 8;
  *(f32x4*)(op) = o0;
  *(f32x4*)(op + 4) = o1;
}

extern "C" void kernel_launch(void* const* d_in, const int* in_sizes, int n_in,
                              void* d_out, int out_size, void* d_ws,
                              size_t ws_size, hipStream_t stream) {
  const float* x = (const float*)d_in[0];
  const int* mask = (const int*)d_in[1];
  const float* Wq = (const float*)d_in[2];
  const float* bq = (const float*)d_in[3];
  const float* Wk = (const float*)d_in[4];
  const float* bk = (const float*)d_in[5];
  const float* Wv = (const float*)d_in[6];
  const float* bv = (const float*)d_in[7];
  const float* pe = (const float*)d_in[8];
  const float* Wo = (const float*)d_in[9];
  const float* bo = (const float*)d_in[10];
  const float* gamma = (const float*)d_in[11];
  const float* beta = (const float*)d_in[12];
  float* out = (float*)d_out;

  char* p = (char*)d_ws;
  unsigned short* xb = (unsigned short*)p; p += (size_t)4194304 * 2;
  unsigned short* Wt = (unsigned short*)p; p += (size_t)2048 * 512 * 2;
  unsigned short* qb = (unsigned short*)p; p += (size_t)4194304 * 2;
  unsigned short* kb = (unsigned short*)p; p += (size_t)4194304 * 2;
  unsigned short* vb = (unsigned short*)p; p += (size_t)4194304 * 2;
  unsigned short* vT = (unsigned short*)p; p += (size_t)4194304 * 2;
  unsigned short* ao = (unsigned short*)p; p += (size_t)4194304 * 2;
  float* proj = (float*)p; p += (size_t)4194304 * 4;
  unsigned int* mb = (unsigned int*)p; p += (size_t)524288 * 4;

  prep_kernel<<<5120, 256, 0, stream>>>(x, mask, Wq, Wk, Wv, Wo, xb, Wt, mb);
  gemm_kernel<<<dim3(24, 128), 256, 0, stream>>>(xb, Wt, 0, qb, kb, vb, bq, bk,
                                                 bv, pe, nullptr, nullptr);
  vtrans_kernel<<<dim3(32, 32), 256, 0, stream>>>(vb, vT);
  attn_kernel<<<dim3(32, 32), 256, 0, stream>>>(qb, kb, vT, mb,
                                                out + 4194304, ao);
  gemm_kernel<<<dim3(8, 128), 256, 0, stream>>>(
      ao, Wt + (size_t)1536 * 512, 1, nullptr, nullptr, nullptr, nullptr,
      nullptr, nullptr, nullptr, proj, bo);
  ln_kernel<<<2048, 256, 0, stream>>>(proj, gamma, beta, out);
}

// Round 3
// 1000.530 us; speedup vs baseline: 1.0165x; 1.0165x over previous
//
#include <hip/hip_runtime.h>
#include <hip/hip_bf16.h>

typedef __attribute__((ext_vector_type(8))) __bf16 bf16x8;
typedef __attribute__((ext_vector_type(8))) unsigned short u16x8;
typedef __attribute__((ext_vector_type(4))) float f32x4;
typedef __attribute__((ext_vector_type(4))) int i32x4;
typedef __attribute__((ext_vector_type(4))) unsigned int u32x4;

#define NB 4
#define NS 2048
#define NH 8
#define NHD 64
#define NDH 512

__device__ __forceinline__ unsigned short f2bf(float f) {
  union { float f; unsigned int u; } v; v.f = f;
  unsigned int r = v.u + 0x7FFFu + ((v.u >> 16) & 1u);
  return (unsigned short)(r >> 16);
}

__device__ __forceinline__ f32x4 MFMA(u16x8 a, u16x8 b, f32x4 c) {
  return __builtin_amdgcn_mfma_f32_16x16x32_bf16(
      __builtin_bit_cast(bf16x8, a), __builtin_bit_cast(bf16x8, b), c, 0, 0, 0);
}

// ---------------- prep: x->bf16, W transpose->bf16 [N,K], mask->bits ----------
__global__ __launch_bounds__(256) void prep_kernel(
    const float* __restrict__ x, const int* __restrict__ mask,
    const float* __restrict__ Wq, const float* __restrict__ Wk,
    const float* __restrict__ Wv, const float* __restrict__ Wo,
    unsigned short* __restrict__ xb, unsigned short* __restrict__ Wt,
    unsigned int* __restrict__ mb) {
  const int bid = blockIdx.x, t = threadIdx.x;
  if (bid < 2048) {
    size_t base = ((size_t)bid * 256 + t) * 8;
    f32x4 a = *(const f32x4*)(x + base);
    f32x4 b = *(const f32x4*)(x + base + 4);
    u16x8 o;
    o[0] = f2bf(a[0]); o[1] = f2bf(a[1]); o[2] = f2bf(a[2]); o[3] = f2bf(a[3]);
    o[4] = f2bf(b[0]); o[5] = f2bf(b[1]); o[6] = f2bf(b[2]); o[7] = f2bf(b[3]);
    *(u16x8*)(xb + base) = o;
  } else if (bid < 3072) {
    __shared__ float lds[32][33];
    int wb = bid - 2048;
    int mat = wb >> 8, tile = wb & 255, tr = tile >> 4, tc = tile & 15;
    const float* W = (mat == 0) ? Wq : (mat == 1) ? Wk : (mat == 2) ? Wv : Wo;
    int col = t & 31, rbase = t >> 5;
    for (int i = 0; i < 4; ++i) {
      int row = rbase + i * 8;
      lds[row][col] = W[(size_t)(tr * 32 + row) * 512 + tc * 32 + col];
    }
    __syncthreads();
    for (int i = 0; i < 4; ++i) {
      int row = rbase + i * 8;  // j-local
      Wt[((size_t)(mat * 512 + tc * 32 + row)) * 512 + tr * 32 + col] =
          f2bf(lds[col][row]);
    }
  } else {
    // ballot-based mask packing: each wave reads 64 consecutive ints
    // (256B coalesced), __ballot gives the 64-bit pack, lane 0 stores 8B.
    const int lane = t & 63;
    const int gw = (bid - 3072) * 4 + (t >> 6);
    const int* mpw = mask + (size_t)gw * 2048;
    unsigned long long* mbw = (unsigned long long*)(mb + (size_t)gw * 64);
    for (int i = 0; i < 32; ++i) {
      int m = mpw[i * 64 + lane];
      unsigned long long bits = __ballot(m != 0);
      if (lane == 0) mbw[i] = bits;
    }
  }
}

// ---------------- GEMM: C[M,N] = A[M,512] x Bt[N,512]^T ----------------------
// mode 0: N=1536, epilogue bias+pe, scatter to q/k/v [B,H,S,hd] bf16
// mode 1: N=512, epilogue +bo, write fp32 proj [M,512]
__global__ __launch_bounds__(256) void gemm_kernel(
    const unsigned short* __restrict__ A, const unsigned short* __restrict__ Bt,
    int mode, unsigned short* __restrict__ qb, unsigned short* __restrict__ kb,
    unsigned short* __restrict__ vb, const float* __restrict__ bq,
    const float* __restrict__ bk, const float* __restrict__ bv,
    const float* __restrict__ pe, float* __restrict__ proj,
    const float* __restrict__ bo) {
  const int t = threadIdx.x;
  const int w = t >> 6, lane = t & 63, l15 = lane & 15, quad = lane >> 4;
  const int n0 = blockIdx.x * 64, m0 = blockIdx.y * 64;
  __shared__ unsigned short a_lds[64 * 40];
  __shared__ unsigned short b_lds[64 * 40];
  f32x4 acc[4] = {};
  const int srow = t >> 2, sc8 = (t & 3) * 8;
  for (int k0 = 0; k0 < 512; k0 += 32) {
    u16x8 av = *(const u16x8*)(A + (size_t)(m0 + srow) * 512 + k0 + sc8);
    u16x8 bvv = *(const u16x8*)(Bt + (size_t)(n0 + srow) * 512 + k0 + sc8);
    __syncthreads();
    *(u16x8*)(a_lds + srow * 40 + sc8) = av;
    *(u16x8*)(b_lds + srow * 40 + sc8) = bvv;
    __syncthreads();
    u16x8 af = *(const u16x8*)(a_lds + (16 * w + l15) * 40 + quad * 8);
    for (int nt = 0; nt < 4; ++nt) {
      u16x8 bf_ = *(const u16x8*)(b_lds + (nt * 16 + l15) * 40 + quad * 8);
      acc[nt] = MFMA(af, bf_, acc[nt]);
    }
  }
  if (mode == 0) {
    for (int nt = 0; nt < 4; ++nt) {
      int j = n0 + nt * 16 + l15;
      int sel = j >> 9, jj = j & 511;
      int h = jj >> 6, hd = jj & 63;
      float bias = (sel == 0) ? bq[jj] : (sel == 1) ? bk[jj] : bv[jj];
      unsigned short* dst = (sel == 0) ? qb : (sel == 1) ? kb : vb;
      for (int r = 0; r < 4; ++r) {
        int m = m0 + 16 * w + quad * 4 + r;
        int bb = m >> 11, s = m & 2047;
        float v = acc[nt][r] + bias;
        if (sel < 2) v += pe[(size_t)s * 512 + jj];
        dst[(((size_t)bb * NH + h) * NS + s) * NHD + hd] = f2bf(v);
      }
    }
  } else {
    for (int nt = 0; nt < 4; ++nt) {
      int j = n0 + nt * 16 + l15;
      float bias = bo[j];
      for (int r = 0; r < 4; ++r) {
        int m = m0 + 16 * w + quad * 4 + r;
        proj[(size_t)m * 512 + j] = acc[nt][r] + bias;
      }
    }
  }
}

// ---------------- v [BH,S,hd] -> vT [BH,hd,S] --------------------------------
__global__ __launch_bounds__(256) void vtrans_kernel(
    const unsigned short* __restrict__ v, unsigned short* __restrict__ vT) {
  const int bh = blockIdx.y, st = blockIdx.x, t = threadIdx.x;
  const int s0 = st * 64;
  __shared__ unsigned int ldsT[64 * 36];
  int sp = t & 31, c8 = t >> 5;
  const unsigned short* vp = v + ((size_t)bh * NS + s0 + 2 * sp) * NHD + c8 * 8;
  u16x8 a = *(const u16x8*)(vp);
  u16x8 b = *(const u16x8*)(vp + NHD);
  for (int i = 0; i < 8; ++i) {
    unsigned int word = (unsigned int)a[i] | ((unsigned int)b[i] << 16);
    ldsT[(c8 * 8 + i) * 36 + sp] = word;
  }
  __syncthreads();
  int hd = t >> 2, cc = t & 3;
  u32x4 w0 = *(const u32x4*)(ldsT + hd * 36 + cc * 8);
  u32x4 w1 = *(const u32x4*)(ldsT + hd * 36 + cc * 8 + 4);
  unsigned short* op = vT + ((size_t)bh * NHD + hd) * NS + s0 + cc * 16;
  *(u32x4*)(op) = w0;
  *(u32x4*)(op + 8) = w1;
}

// ---------------- attention: per (bh, 64-row q tile) -------------------------
// Barrier-free + register-prefetched. K fragments are double-buffered in VGPRs
// one kt-tile ahead (the round-2 regression was unpipelined per-iteration
// global loads stalling on vmcnt before every MFMA). V fragments are issued at
// iteration start and consumed after softmax (~400cy cover). XCD-aware (bh,qt)
// remap keeps all 32 q-tiles of one head on one XCD (per-XCD L2 footprint
// ~3MB < 4MB), eliminating the 3x HBM re-fetch. Per-wave p stripe (stride 72
// shorts, 16B-aligned) needs no __syncthreads. setprio(1) around MFMA
// clusters: independent waves at different phases = the regime where it pays.
__global__ __launch_bounds__(256, 3) void attn_kernel(
    const unsigned short* __restrict__ qg, const unsigned short* __restrict__ kg,
    const unsigned short* __restrict__ vTg, const unsigned int* __restrict__ mb,
    float* __restrict__ attnp_base, unsigned short* __restrict__ ao) {
  const int L = blockIdx.y * 32 + blockIdx.x;
  const int bh = L & 31, qt = L >> 5;  // same-bh blocks share an XCD (L%8 fixed)
  const int bb = bh >> 3, hh = bh & 7;
  const int t = threadIdx.x, w = t >> 6, lane = t & 63;
  const int l15 = lane & 15, quad = lane >> 4;
  const int sq0 = qt * 64;

  __shared__ unsigned short p_lds[4][16 * 72];  // per-wave stripe, stride 72
  unsigned short* pw = &p_lds[w][0];

  const unsigned short* qptr = qg + ((size_t)bh * NS + sq0 + 16 * w) * NHD;
  const unsigned short* kbase = kg + (size_t)bh * NS * NHD;
  const unsigned short* vtbase = vTg + (size_t)bh * NHD * NS;

  const u16x8 a0 = *(const u16x8*)(qptr + l15 * 64 + quad * 8);
  const u16x8 a1 = *(const u16x8*)(qptr + l15 * 64 + 32 + quad * 8);

  float mI[4], lI[4];
#pragma unroll
  for (int r = 0; r < 4; ++r) { mI[r] = -1e30f; lI[r] = 0.f; }
  const size_t mrow0 = ((size_t)bb * NS + sq0 + 16 * w + quad * 4) * 64;

  auto loadK8 = [&](const unsigned short* kp, u16x8 (&f)[8]) {
#pragma unroll
    for (int nt = 0; nt < 4; ++nt) {
      f[2 * nt] = *(const u16x8*)(kp + (nt * 16 + l15) * 64 + quad * 8);
      f[2 * nt + 1] = *(const u16x8*)(kp + (nt * 16 + l15) * 64 + 32 + quad * 8);
    }
  };

  auto stepA = [&](const u16x8 (&f)[8], int kt) {
    f32x4 sc[4];
    __builtin_amdgcn_s_setprio(1);
#pragma unroll
    for (int nt = 0; nt < 4; ++nt) {
      f32x4 acc = {0.f, 0.f, 0.f, 0.f};
      acc = MFMA(a0, f[2 * nt], acc);
      acc = MFMA(a1, f[2 * nt + 1], acc);
      sc[nt] = acc;
    }
    __builtin_amdgcn_s_setprio(0);
    unsigned int mw0[4], mw1[4];
#pragma unroll
    for (int r = 0; r < 4; ++r) {
      mw0[r] = mb[mrow0 + (size_t)r * 64 + kt * 2];
      mw1[r] = mb[mrow0 + (size_t)r * 64 + kt * 2 + 1];
    }
    float tm[4] = {-1e30f, -1e30f, -1e30f, -1e30f};
#pragma unroll
    for (int nt = 0; nt < 4; ++nt) {
      int cl = nt * 16 + l15;
#pragma unroll
      for (int r = 0; r < 4; ++r) {
        float sv = sc[nt][r] * 0.125f;
        unsigned int wsel = (cl < 32) ? mw0[r] : mw1[r];
        if (!((wsel >> (cl & 31)) & 1u)) sv = -1e30f;
        sc[nt][r] = sv;
        tm[r] = fmaxf(tm[r], sv);
      }
    }
#pragma unroll
    for (int r = 0; r < 4; ++r) {
      float mN = fmaxf(mI[r], tm[r]);
      float sum = 0.f;
#pragma unroll
      for (int nt = 0; nt < 4; ++nt) sum += __expf(sc[nt][r] - mN);
      lI[r] = lI[r] * __expf(mI[r] - mN) + sum;
      mI[r] = mN;
    }
  };

  // pass A: register-double-buffered K prefetch, no LDS, no barriers
  {
    u16x8 fA[8], fB[8];
    loadK8(kbase, fA);
    for (int kt = 0; kt < 32; kt += 2) {
      loadK8(kbase + (size_t)((kt + 1) & 31) * (64 * NHD), fB);
      stepA(fA, kt);
      loadK8(kbase + (size_t)((kt + 2) & 31) * (64 * NHD), fA);
      stepA(fB, kt + 1);
    }
  }
  // merge stats across the 16 l15 lanes (they hold the same 4 rows)
#pragma unroll
  for (int off = 1; off < 16; off <<= 1) {
#pragma unroll
    for (int r = 0; r < 4; ++r) {
      float mo = __shfl_xor(mI[r], off, 64);
      float lo = __shfl_xor(lI[r], off, 64);
      float mN = fmaxf(mI[r], mo);
      lI[r] = lI[r] * __expf(mI[r] - mN) + lo * __expf(mo - mN);
      mI[r] = mN;
    }
  }
  float invl[4];
#pragma unroll
  for (int r = 0; r < 4; ++r) invl[r] = 1.0f / lI[r];

  float* attnp = attnp_base + ((size_t)bh * NS + sq0 + 16 * w) * NS;
  f32x4 oacc[4] = {};

  auto loadV8 = [&](const unsigned short* vp, u16x8 (&f)[8]) {
#pragma unroll
    for (int nto = 0; nto < 4; ++nto) {
      f[2 * nto] = *(const u16x8*)(vp + (size_t)(nto * 16 + l15) * NS + quad * 8);
      f[2 * nto + 1] =
          *(const u16x8*)(vp + (size_t)(nto * 16 + l15) * NS + 32 + quad * 8);
    }
  };

  auto stepB = [&](const u16x8 (&f)[8], const u16x8 (&vv)[8], int kt) {
    f32x4 sc[4];
    __builtin_amdgcn_s_setprio(1);
#pragma unroll
    for (int nt = 0; nt < 4; ++nt) {
      f32x4 acc = {0.f, 0.f, 0.f, 0.f};
      acc = MFMA(a0, f[2 * nt], acc);
      acc = MFMA(a1, f[2 * nt + 1], acc);
      sc[nt] = acc;
    }
    __builtin_amdgcn_s_setprio(0);
    unsigned int mw0[4], mw1[4];
#pragma unroll
    for (int r = 0; r < 4; ++r) {
      mw0[r] = mb[mrow0 + (size_t)r * 64 + kt * 2];
      mw1[r] = mb[mrow0 + (size_t)r * 64 + kt * 2 + 1];
    }
#pragma unroll
    for (int nt = 0; nt < 4; ++nt) {
      int cl = nt * 16 + l15;
#pragma unroll
      for (int r = 0; r < 4; ++r) {
        float sv = sc[nt][r] * 0.125f;
        unsigned int wsel = (cl < 32) ? mw0[r] : mw1[r];
        if (!((wsel >> (cl & 31)) & 1u)) sv = -1e30f;
        float pv = __expf(sv - mI[r]) * invl[r];
        attnp[(size_t)(quad * 4 + r) * NS + kt * 64 + cl] = pv;
        pw[(quad * 4 + r) * 72 + cl] = f2bf(pv);
      }
    }
    // order p writes before PV reads (wave-private stripe; DS ops in-order)
    asm volatile("" ::: "memory");
#pragma unroll
    for (int h = 0; h < 2; ++h) {
      u16x8 af = *(const u16x8*)(pw + l15 * 72 + h * 32 + quad * 8);
      __builtin_amdgcn_s_setprio(1);
#pragma unroll
      for (int nto = 0; nto < 4; ++nto)
        oacc[nto] = MFMA(af, vv[2 * nto + h], oacc[nto]);
      __builtin_amdgcn_s_setprio(0);
    }
    asm volatile("" ::: "memory");
  };

  // pass B: K double-buffered in regs; V issued at iter start, consumed late
  {
    u16x8 fA[8], fB[8];
    loadK8(kbase, fA);
    for (int kt = 0; kt < 32; kt += 2) {
      u16x8 vA[8];
      loadV8(vtbase + kt * 64, vA);
      loadK8(kbase + (size_t)((kt + 1) & 31) * (64 * NHD), fB);
      stepB(fA, vA, kt);
      u16x8 vB[8];
      loadV8(vtbase + (kt + 1) * 64, vB);
      loadK8(kbase + (size_t)((kt + 2) & 31) * (64 * NHD), fA);
      stepB(fB, vB, kt + 1);
    }
  }
#pragma unroll
  for (int nto = 0; nto < 4; ++nto)
#pragma unroll
    for (int r = 0; r < 4; ++r) {
      int s = sq0 + 16 * w + quad * 4 + r;
      ao[((size_t)(bb * NS + s)) * NDH + hh * 64 + nto * 16 + l15] =
          f2bf(oacc[nto][r]);
    }
}

// ---------------- layernorm over last dim 512 --------------------------------
__global__ __launch_bounds__(256) void ln_kernel(
    const float* __restrict__ proj, const float* __restrict__ gamma,
    const float* __restrict__ beta, float* __restrict__ out) {
  const int t = threadIdx.x, w = t >> 6, lane = t & 63;
  const int row = blockIdx.x * 4 + w;
  const float* pr = proj + (size_t)row * 512 + lane * 8;
  f32x4 v0 = *(const f32x4*)(pr);
  f32x4 v1 = *(const f32x4*)(pr + 4);
  float s = 0.f, s2 = 0.f;
  for (int j = 0; j < 4; ++j) {
    s += v0[j] + v1[j];
    s2 += v0[j] * v0[j] + v1[j] * v1[j];
  }
  for (int off = 1; off < 64; off <<= 1) {
    s += __shfl_xor(s, off, 64);
    s2 += __shfl_xor(s2, off, 64);
  }
  float mu = s * (1.f / 512.f);
  float var = s2 * (1.f / 512.f) - mu * mu;
  float rs = rsqrtf(var + 1e-5f);
  f32x4 g0 = *(const f32x4*)(gamma + lane * 8);
  f32x4 g1 = *(const f32x4*)(gamma + lane * 8 + 4);
  f32x4 be0 = *(const f32x4*)(beta + lane * 8);
  f32x4 be1 = *(const f32x4*)(beta + lane * 8 + 4);
  f32x4 o0, o1;
  for (int j = 0; j < 4; ++j) {
    o0[j] = (v0[j] - mu) * rs * g0[j] + be0[j];
    o1[j] = (v1[j] - mu) * rs * g1[j] + be1[j];
  }
  float* op = out + (size_t)row * 512 + lane * 8;
  *(f32x4*)(op) = o0;
  *(f32x4*)(op + 4) = o1;
}

extern "C" void kernel_launch(void* const* d_in, const int* in_sizes, int n_in,
                              void* d_out, int out_size, void* d_ws,
                              size_t ws_size, hipStream_t stream) {
  const float* x = (const float*)d_in[0];
  const int* mask = (const int*)d_in[1];
  const float* Wq = (const float*)d_in[2];
  const float* bq = (const float*)d_in[3];
  const float* Wk = (const float*)d_in[4];
  const float* bk = (const float*)d_in[5];
  const float* Wv = (const float*)d_in[6];
  const float* bv = (const float*)d_in[7];
  const float* pe = (const float*)d_in[8];
  const float* Wo = (const float*)d_in[9];
  const float* bo = (const float*)d_in[10];
  const float* gamma = (const float*)d_in[11];
  const float* beta = (const float*)d_in[12];
  float* out = (float*)d_out;

  char* p = (char*)d_ws;
  unsigned short* xb = (unsigned short*)p; p += (size_t)4194304 * 2;
  unsigned short* Wt = (unsigned short*)p; p += (size_t)2048 * 512 * 2;
  unsigned short* qb = (unsigned short*)p; p += (size_t)4194304 * 2;
  unsigned short* kb = (unsigned short*)p; p += (size_t)4194304 * 2;
  unsigned short* vb = (unsigned short*)p; p += (size_t)4194304 * 2;
  unsigned short* vT = (unsigned short*)p; p += (size_t)4194304 * 2;
  unsigned short* ao = (unsigned short*)p; p += (size_t)4194304 * 2;
  float* proj = (float*)p; p += (size_t)4194304 * 4;
  unsigned int* mb = (unsigned int*)p; p += (size_t)524288 * 4;

  prep_kernel<<<5120, 256, 0, stream>>>(x, mask, Wq, Wk, Wv, Wo, xb, Wt, mb);
  gemm_kernel<<<dim3(24, 128), 256, 0, stream>>>(xb, Wt, 0, qb, kb, vb, bq, bk,
                                                 bv, pe, nullptr, nullptr);
  vtrans_kernel<<<dim3(32, 32), 256, 0, stream>>>(vb, vT);
  attn_kernel<<<dim3(32, 32), 256, 0, stream>>>(qb, kb, vT, mb,
                                                out + 4194304, ao);
  gemm_kernel<<<dim3(8, 128), 256, 0, stream>>>(
      ao, Wt + (size_t)1536 * 512, 1, nullptr, nullptr, nullptr, nullptr,
      nullptr, nullptr, nullptr, proj, bo);
  ln_kernel<<<2048, 256, 0, stream>>>(proj, gamma, beta, out);
}

// Round 4
// 873.199 us; speedup vs baseline: 1.1647x; 1.1458x over previous
//
#include <hip/hip_runtime.h>
#include <hip/hip_bf16.h>

typedef __attribute__((ext_vector_type(8))) __bf16 bf16x8;
typedef __attribute__((ext_vector_type(8))) unsigned short u16x8;
typedef __attribute__((ext_vector_type(4))) float f32x4;
typedef __attribute__((ext_vector_type(4))) int i32x4;
typedef __attribute__((ext_vector_type(4))) unsigned int u32x4;

#define NB 4
#define NS 2048
#define NH 8
#define NHD 64
#define NDH 512

#define GLOAD16(g, l)                                        \
  __builtin_amdgcn_global_load_lds(                          \
      (__attribute__((address_space(1))) void*)(g),          \
      (__attribute__((address_space(3))) void*)(l), 16, 0, 0)

__device__ __forceinline__ unsigned short f2bf(float f) {
  union { float f; unsigned int u; } v; v.f = f;
  unsigned int r = v.u + 0x7FFFu + ((v.u >> 16) & 1u);
  return (unsigned short)(r >> 16);
}

__device__ __forceinline__ f32x4 MFMA(u16x8 a, u16x8 b, f32x4 c) {
  return __builtin_amdgcn_mfma_f32_16x16x32_bf16(
      __builtin_bit_cast(bf16x8, a), __builtin_bit_cast(bf16x8, b), c, 0, 0, 0);
}

// ---------------- prep: x->bf16, W transpose->bf16 [N,K], mask->bits ----------
__global__ __launch_bounds__(256) void prep_kernel(
    const float* __restrict__ x, const int* __restrict__ mask,
    const float* __restrict__ Wq, const float* __restrict__ Wk,
    const float* __restrict__ Wv, const float* __restrict__ Wo,
    unsigned short* __restrict__ xb, unsigned short* __restrict__ Wt,
    unsigned int* __restrict__ mb) {
  const int bid = blockIdx.x, t = threadIdx.x;
  if (bid < 2048) {
    size_t base = ((size_t)bid * 256 + t) * 8;
    f32x4 a = *(const f32x4*)(x + base);
    f32x4 b = *(const f32x4*)(x + base + 4);
    u16x8 o;
    o[0] = f2bf(a[0]); o[1] = f2bf(a[1]); o[2] = f2bf(a[2]); o[3] = f2bf(a[3]);
    o[4] = f2bf(b[0]); o[5] = f2bf(b[1]); o[6] = f2bf(b[2]); o[7] = f2bf(b[3]);
    *(u16x8*)(xb + base) = o;
  } else if (bid < 3072) {
    __shared__ float lds[32][33];
    int wb = bid - 2048;
    int mat = wb >> 8, tile = wb & 255, tr = tile >> 4, tc = tile & 15;
    const float* W = (mat == 0) ? Wq : (mat == 1) ? Wk : (mat == 2) ? Wv : Wo;
    int col = t & 31, rbase = t >> 5;
    for (int i = 0; i < 4; ++i) {
      int row = rbase + i * 8;
      lds[row][col] = W[(size_t)(tr * 32 + row) * 512 + tc * 32 + col];
    }
    __syncthreads();
    for (int i = 0; i < 4; ++i) {
      int row = rbase + i * 8;  // j-local
      Wt[((size_t)(mat * 512 + tc * 32 + row)) * 512 + tr * 32 + col] =
          f2bf(lds[col][row]);
    }
  } else {
    // ballot-based mask packing: each wave reads 64 consecutive ints
    // (256B coalesced), __ballot gives the 64-bit pack, lane 0 stores 8B.
    const int lane = t & 63;
    const int gw = (bid - 3072) * 4 + (t >> 6);
    const int* mpw = mask + (size_t)gw * 2048;
    unsigned long long* mbw = (unsigned long long*)(mb + (size_t)gw * 64);
    for (int i = 0; i < 32; ++i) {
      int m = mpw[i * 64 + lane];
      unsigned long long bits = __ballot(m != 0);
      if (lane == 0) mbw[i] = bits;
    }
  }
}

// ---------------- GEMM: C[M,N] = A[M,512] x Bt[N,512]^T ----------------------
// mode 0: N=1536, epilogue bias+pe, scatter to q/k/v [B,H,S,hd] bf16
// mode 1: N=512, epilogue +bo, write fp32 proj [M,512]
__global__ __launch_bounds__(256) void gemm_kernel(
    const unsigned short* __restrict__ A, const unsigned short* __restrict__ Bt,
    int mode, unsigned short* __restrict__ qb, unsigned short* __restrict__ kb,
    unsigned short* __restrict__ vb, const float* __restrict__ bq,
    const float* __restrict__ bk, const float* __restrict__ bv,
    const float* __restrict__ pe, float* __restrict__ proj,
    const float* __restrict__ bo) {
  const int t = threadIdx.x;
  const int w = t >> 6, lane = t & 63, l15 = lane & 15, quad = lane >> 4;
  const int n0 = blockIdx.x * 64, m0 = blockIdx.y * 64;
  __shared__ unsigned short a_lds[64 * 40];
  __shared__ unsigned short b_lds[64 * 40];
  f32x4 acc[4] = {};
  const int srow = t >> 2, sc8 = (t & 3) * 8;
  for (int k0 = 0; k0 < 512; k0 += 32) {
    u16x8 av = *(const u16x8*)(A + (size_t)(m0 + srow) * 512 + k0 + sc8);
    u16x8 bvv = *(const u16x8*)(Bt + (size_t)(n0 + srow) * 512 + k0 + sc8);
    __syncthreads();
    *(u16x8*)(a_lds + srow * 40 + sc8) = av;
    *(u16x8*)(b_lds + srow * 40 + sc8) = bvv;
    __syncthreads();
    u16x8 af = *(const u16x8*)(a_lds + (16 * w + l15) * 40 + quad * 8);
    for (int nt = 0; nt < 4; ++nt) {
      u16x8 bf_ = *(const u16x8*)(b_lds + (nt * 16 + l15) * 40 + quad * 8);
      acc[nt] = MFMA(af, bf_, acc[nt]);
    }
  }
  if (mode == 0) {
    for (int nt = 0; nt < 4; ++nt) {
      int j = n0 + nt * 16 + l15;
      int sel = j >> 9, jj = j & 511;
      int h = jj >> 6, hd = jj & 63;
      float bias = (sel == 0) ? bq[jj] : (sel == 1) ? bk[jj] : bv[jj];
      unsigned short* dst = (sel == 0) ? qb : (sel == 1) ? kb : vb;
      for (int r = 0; r < 4; ++r) {
        int m = m0 + 16 * w + quad * 4 + r;
        int bb = m >> 11, s = m & 2047;
        float v = acc[nt][r] + bias;
        if (sel < 2) v += pe[(size_t)s * 512 + jj];
        dst[(((size_t)bb * NH + h) * NS + s) * NHD + hd] = f2bf(v);
      }
    }
  } else {
    for (int nt = 0; nt < 4; ++nt) {
      int j = n0 + nt * 16 + l15;
      float bias = bo[j];
      for (int r = 0; r < 4; ++r) {
        int m = m0 + 16 * w + quad * 4 + r;
        proj[(size_t)m * 512 + j] = acc[nt][r] + bias;
      }
    }
  }
}

// ---------------- v [BH,S,hd] -> vT [BH,hd,S] --------------------------------
__global__ __launch_bounds__(256) void vtrans_kernel(
    const unsigned short* __restrict__ v, unsigned short* __restrict__ vT) {
  const int bh = blockIdx.y, st = blockIdx.x, t = threadIdx.x;
  const int s0 = st * 64;
  __shared__ unsigned int ldsT[64 * 36];
  int sp = t & 31, c8 = t >> 5;
  const unsigned short* vp = v + ((size_t)bh * NS + s0 + 2 * sp) * NHD + c8 * 8;
  u16x8 a = *(const u16x8*)(vp);
  u16x8 b = *(const u16x8*)(vp + NHD);
  for (int i = 0; i < 8; ++i) {
    unsigned int word = (unsigned int)a[i] | ((unsigned int)b[i] << 16);
    ldsT[(c8 * 8 + i) * 36 + sp] = word;
  }
  __syncthreads();
  int hd = t >> 2, cc = t & 3;
  u32x4 w0 = *(const u32x4*)(ldsT + hd * 36 + cc * 8);
  u32x4 w1 = *(const u32x4*)(ldsT + hd * 36 + cc * 8 + 4);
  unsigned short* op = vT + ((size_t)bh * NHD + hd) * NS + s0 + cc * 16;
  *(u32x4*)(op) = w0;
  *(u32x4*)(op + 8) = w1;
}

// ---------------- attention: per (bh, 64-row q tile) -------------------------
// Async pipeline: K/V tiles staged HBM->LDS via global_load_lds (16B), double
// buffered; raw s_barrier + hand-placed counted vmcnt (waits only for the
// PREVIOUS tile's loads, which had a full iteration of runway; the just-issued
// prefetch stays in flight). Both-sides XOR chunk swizzle (c ^= row&7) on the
// pre-swizzled global source and on fragment ds_read_b128 -> 2-way banks.
// Softmax without running max (scores bounded): pass A accumulates
// sum(exp2(s*C)) only; merge = 4 shuffle-adds. P stores are non-temporal so
// the 537MB stream doesn't evict the K/V working set from L2. XCD-pinned
// (bh = L&31 -> XCD bh%8). LDS 41984B -> 3 blocks/CU.
__global__ __launch_bounds__(256, 3) void attn_kernel(
    const unsigned short* __restrict__ qg, const unsigned short* __restrict__ kg,
    const unsigned short* __restrict__ vTg, const unsigned int* __restrict__ mb,
    float* __restrict__ attnp_base, unsigned short* __restrict__ ao) {
  const int L = blockIdx.y * 32 + blockIdx.x;
  const int bh = L & 31, qt = L >> 5;
  const int bb = bh >> 3, hh = bh & 7;
  const int t = threadIdx.x, w = t >> 6, lane = t & 63;
  const int l15 = lane & 15, quad = lane >> 4;
  const int sq0 = qt * 64;
  const float CEXP = 0.125f * 1.44269504f;

  __shared__ __align__(16) unsigned short k_lds[2][4096];
  __shared__ __align__(16) unsigned short v_lds[2][4096];
  __shared__ __align__(16) unsigned short p_lds[4][16 * 72];
  unsigned short* pw = &p_lds[w][0];

  const unsigned short* qptr = qg + ((size_t)bh * NS + sq0 + 16 * w) * NHD;
  const unsigned short* kbase = kg + (size_t)bh * NS * NHD;
  const unsigned short* vtbase = vTg + (size_t)bh * NHD * NS;

  const u16x8 a0 = *(const u16x8*)(qptr + l15 * 64 + quad * 8);
  const u16x8 a1 = *(const u16x8*)(qptr + l15 * 64 + 32 + quad * 8);

  // staging geometry: slot s = w*128 + j*64 + lane covers LDS shorts
  // [s*8, s*8+8); row = s>>3, stored chunk = s&7, source chunk = (s&7)^(row&7)
  const int s0_ = w * 128 + lane;
  const int row0 = s0_ >> 3, c0 = (s0_ & 7) ^ (row0 & 7);
  const int s1_ = s0_ + 64;
  const int row1 = s1_ >> 3, c1 = (s1_ & 7) ^ (row1 & 7);
  const int loff = w * 1024;  // shorts; j=1 at +512

  float lI[4] = {0.f, 0.f, 0.f, 0.f};
  const size_t mrow0 = ((size_t)bb * NS + sq0 + 16 * w + quad * 4) * 64;
  const int swz = (l15 & 7);

  auto stageK = [&](int kt, int buf) {
    GLOAD16(kbase + ((size_t)(kt * 64 + row0)) * NHD + c0 * 8, &k_lds[buf][loff]);
    GLOAD16(kbase + ((size_t)(kt * 64 + row1)) * NHD + c1 * 8,
            &k_lds[buf][loff + 512]);
  };
  auto stageV = [&](int kt, int buf) {
    GLOAD16(vtbase + (size_t)row0 * NS + kt * 64 + c0 * 8, &v_lds[buf][loff]);
    GLOAD16(vtbase + (size_t)row1 * NS + kt * 64 + c1 * 8,
            &v_lds[buf][loff + 512]);
  };
  auto qk = [&](const unsigned short* kb_, f32x4 (&sc)[4]) {
    __builtin_amdgcn_s_setprio(1);
#pragma unroll
    for (int nt = 0; nt < 4; ++nt) {
      int R = nt * 16 + l15;
      u16x8 b0 = *(const u16x8*)(kb_ + R * 64 + ((quad ^ swz) << 3));
      u16x8 b1 = *(const u16x8*)(kb_ + R * 64 + (((quad + 4) ^ swz) << 3));
      f32x4 acc = {0.f, 0.f, 0.f, 0.f};
      acc = MFMA(a0, b0, acc);
      acc = MFMA(a1, b1, acc);
      sc[nt] = acc;
    }
    __builtin_amdgcn_s_setprio(0);
  };

  // ---------------- pass A: row sums only ----------------
  stageK(0, 0);
  for (int kt = 0; kt < 32; ++kt) {
    const int cur = kt & 1;
    asm volatile("s_waitcnt lgkmcnt(0)" ::: "memory");
    __builtin_amdgcn_s_barrier();
    stageK((kt + 1) & 31, cur ^ 1);
    asm volatile("s_waitcnt vmcnt(2)" ::: "memory");
    __builtin_amdgcn_sched_barrier(0);
    __builtin_amdgcn_s_barrier();
    unsigned int mw0[4], mw1[4];
#pragma unroll
    for (int r = 0; r < 4; ++r) {
      mw0[r] = mb[mrow0 + (size_t)r * 64 + kt * 2];
      mw1[r] = mb[mrow0 + (size_t)r * 64 + kt * 2 + 1];
    }
    f32x4 sc[4];
    qk(&k_lds[cur][0], sc);
#pragma unroll
    for (int nt = 0; nt < 4; ++nt) {
      int cl = nt * 16 + l15;
#pragma unroll
      for (int r = 0; r < 4; ++r) {
        float sv = sc[nt][r];
        unsigned int wsel = (cl < 32) ? mw0[r] : mw1[r];
        if (!((wsel >> (cl & 31)) & 1u)) sv = -1e30f;
        lI[r] += exp2f(sv * CEXP);
      }
    }
  }
  // merge sums across the 16 l15 lanes (they hold the same 4 rows)
#pragma unroll
  for (int off = 1; off < 16; off <<= 1)
#pragma unroll
    for (int r = 0; r < 4; ++r) lI[r] += __shfl_xor(lI[r], off, 64);
  float invl[4];
#pragma unroll
  for (int r = 0; r < 4; ++r) invl[r] = 1.0f / lI[r];

  float* attnp = attnp_base + ((size_t)bh * NS + sq0 + 16 * w) * NS;
  f32x4 oacc[4] = {};

  // ---------------- pass B: P write + O = P V ----------------
  // k_lds[0] already holds tile 0 (pass A's last prefetch targets tile 0).
  stageV(0, 0);
  for (int kt = 0; kt < 32; ++kt) {
    const int cur = kt & 1;
    asm volatile("s_waitcnt lgkmcnt(0)" ::: "memory");
    __builtin_amdgcn_s_barrier();
    stageK((kt + 1) & 31, cur ^ 1);
    stageV((kt + 1) & 31, cur ^ 1);
    asm volatile("s_waitcnt vmcnt(4)" ::: "memory");
    __builtin_amdgcn_sched_barrier(0);
    __builtin_amdgcn_s_barrier();
    unsigned int mw0[4], mw1[4];
#pragma unroll
    for (int r = 0; r < 4; ++r) {
      mw0[r] = mb[mrow0 + (size_t)r * 64 + kt * 2];
      mw1[r] = mb[mrow0 + (size_t)r * 64 + kt * 2 + 1];
    }
    f32x4 sc[4];
    qk(&k_lds[cur][0], sc);
#pragma unroll
    for (int nt = 0; nt < 4; ++nt) {
      int cl = nt * 16 + l15;
#pragma unroll
      for (int r = 0; r < 4; ++r) {
        float sv = sc[nt][r];
        unsigned int wsel = (cl < 32) ? mw0[r] : mw1[r];
        if (!((wsel >> (cl & 31)) & 1u)) sv = -1e30f;
        float pv = exp2f(sv * CEXP) * invl[r];
        __builtin_nontemporal_store(
            pv, attnp + (size_t)(quad * 4 + r) * NS + kt * 64 + cl);
        pw[(quad * 4 + r) * 72 + cl] = f2bf(pv);
      }
    }
    asm volatile("" ::: "memory");  // p writes before PV reads (wave-private)
    const unsigned short* vb_ = &v_lds[cur][0];
#pragma unroll
    for (int h = 0; h < 2; ++h) {
      u16x8 af = *(const u16x8*)(pw + l15 * 72 + h * 32 + quad * 8);
      __builtin_amdgcn_s_setprio(1);
#pragma unroll
      for (int nto = 0; nto < 4; ++nto) {
        int R = nto * 16 + l15;
        u16x8 bf_ =
            *(const u16x8*)(vb_ + R * 64 + (((quad + 4 * h) ^ swz) << 3));
        oacc[nto] = MFMA(af, bf_, oacc[nto]);
      }
      __builtin_amdgcn_s_setprio(0);
    }
  }
#pragma unroll
  for (int nto = 0; nto < 4; ++nto)
#pragma unroll
    for (int r = 0; r < 4; ++r) {
      int s = sq0 + 16 * w + quad * 4 + r;
      ao[((size_t)(bb * NS + s)) * NDH + hh * 64 + nto * 16 + l15] =
          f2bf(oacc[nto][r]);
    }
}

// ---------------- layernorm over last dim 512 --------------------------------
__global__ __launch_bounds__(256) void ln_kernel(
    const float* __restrict__ proj, const float* __restrict__ gamma,
    const float* __restrict__ beta, float* __restrict__ out) {
  const int t = threadIdx.x, w = t >> 6, lane = t & 63;
  const int row = blockIdx.x * 4 + w;
  const float* pr = proj + (size_t)row * 512 + lane * 8;
  f32x4 v0 = *(const f32x4*)(pr);
  f32x4 v1 = *(const f32x4*)(pr + 4);
  float s = 0.f, s2 = 0.f;
  for (int j = 0; j < 4; ++j) {
    s += v0[j] + v1[j];
    s2 += v0[j] * v0[j] + v1[j] * v1[j];
  }
  for (int off = 1; off < 64; off <<= 1) {
    s += __shfl_xor(s, off, 64);
    s2 += __shfl_xor(s2, off, 64);
  }
  float mu = s * (1.f / 512.f);
  float var = s2 * (1.f / 512.f) - mu * mu;
  float rs = rsqrtf(var + 1e-5f);
  f32x4 g0 = *(const f32x4*)(gamma + lane * 8);
  f32x4 g1 = *(const f32x4*)(gamma + lane * 8 + 4);
  f32x4 be0 = *(const f32x4*)(beta + lane * 8);
  f32x4 be1 = *(const f32x4*)(beta + lane * 8 + 4);
  f32x4 o0, o1;
  for (int j = 0; j < 4; ++j) {
    o0[j] = (v0[j] - mu) * rs * g0[j] + be0[j];
    o1[j] = (v1[j] - mu) * rs * g1[j] + be1[j];
  }
  float* op = out + (size_t)row * 512 + lane * 8;
  *(f32x4*)(op) = o0;
  *(f32x4*)(op + 4) = o1;
}

extern "C" void kernel_launch(void* const* d_in, const int* in_sizes, int n_in,
                              void* d_out, int out_size, void* d_ws,
                              size_t ws_size, hipStream_t stream) {
  const float* x = (const float*)d_in[0];
  const int* mask = (const int*)d_in[1];
  const float* Wq = (const float*)d_in[2];
  const float* bq = (const float*)d_in[3];
  const float* Wk = (const float*)d_in[4];
  const float* bk = (const float*)d_in[5];
  const float* Wv = (const float*)d_in[6];
  const float* bv = (const float*)d_in[7];
  const float* pe = (const float*)d_in[8];
  const float* Wo = (const float*)d_in[9];
  const float* bo = (const float*)d_in[10];
  const float* gamma = (const float*)d_in[11];
  const float* beta = (const float*)d_in[12];
  float* out = (float*)d_out;

  char* p = (char*)d_ws;
  unsigned short* xb = (unsigned short*)p; p += (size_t)4194304 * 2;
  unsigned short* Wt = (unsigned short*)p; p += (size_t)2048 * 512 * 2;
  unsigned short* qb = (unsigned short*)p; p += (size_t)4194304 * 2;
  unsigned short* kb = (unsigned short*)p; p += (size_t)4194304 * 2;
  unsigned short* vb = (unsigned short*)p; p += (size_t)4194304 * 2;
  unsigned short* vT = (unsigned short*)p; p += (size_t)4194304 * 2;
  unsigned short* ao = (unsigned short*)p; p += (size_t)4194304 * 2;
  float* proj = (float*)p; p += (size_t)4194304 * 4;
  unsigned int* mb = (unsigned int*)p; p += (size_t)524288 * 4;

  prep_kernel<<<5120, 256, 0, stream>>>(x, mask, Wq, Wk, Wv, Wo, xb, Wt, mb);
  gemm_kernel<<<dim3(24, 128), 256, 0, stream>>>(xb, Wt, 0, qb, kb, vb, bq, bk,
                                                 bv, pe, nullptr, nullptr);
  vtrans_kernel<<<dim3(32, 32), 256, 0, stream>>>(vb, vT);
  attn_kernel<<<dim3(32, 32), 256, 0, stream>>>(qb, kb, vT, mb,
                                                out + 4194304, ao);
  gemm_kernel<<<dim3(8, 128), 256, 0, stream>>>(
      ao, Wt + (size_t)1536 * 512, 1, nullptr, nullptr, nullptr, nullptr,
      nullptr, nullptr, nullptr, proj, bo);
  ln_kernel<<<2048, 256, 0, stream>>>(proj, gamma, beta, out);
}